// Round 11
// baseline (363.009 us; speedup 1.0000x reference)
//
#include <hip/hip_runtime.h>
#include <hip/hip_bf16.h>
#include <hip/hip_fp16.h>

// GCN: gcn_norm -> conv1(relu) -> conv2(relu) -> mean-pool -> MLP head.
// R11: revert to proven R8 agg/sortB (fp16 tables; fp8 FAILED numerics at
// 3.2e-6 vs 5.7e-7 threshold — 8-bit payload is dead). Build-phase tuning:
// EPB 8192 (denser scattered writes), split LDS histograms in sortB,
// zero-based cursors (no initcur kernel).
// fp16 feature buffers, fp32 accumulation everywhere.

#define DIMH 64
#define BSH 7                 // 128 nodes per bucket
#define BSZ 128
#define NBUCK_MAX 1024
#define EPB 8192              // edges per partition block (196 blocks)
#define ESTRIDE 3072          // part region per bucket (mean fill ~2046)
#define CSTRIDE 4096          // padded csr region per bucket (max 3968)

// ---- scatter edges into strided bucket regions (LDS 2-pass, 1 global
//      atomic per (block,bucket); cursor zero-based, memset-cleared) ----
// record: [63:32]=w fp32 bits, [31:8]=src, [7:0]=c_local
__global__ __launch_bounds__(512) void k_part(const int* __restrict__ row,
                                              const int* __restrict__ col,
                                              const float* __restrict__ ew,
                                              int* __restrict__ cursor,
                                              unsigned long long* __restrict__ part,
                                              int E, int nbuck) {
    __shared__ int h[NBUCK_MAX];
    __shared__ int h2[NBUCK_MAX];
    __shared__ int st[NBUCK_MAX];
    for (int i = threadIdx.x; i < nbuck; i += 512) { h[i] = 0; h2[i] = 0; }
    __syncthreads();
    int ebeg = blockIdx.x * EPB;
    int eend = min(ebeg + EPB, E);
    for (int e = ebeg + threadIdx.x; e < eend; e += 512)
        atomicAdd(&h[col[e] >> BSH], 1);
    __syncthreads();
    for (int i = threadIdx.x; i < nbuck; i += 512) {
        int c = h[i];
        st[i] = c ? i * ESTRIDE + atomicAdd(&cursor[i], c) : 0;
    }
    __syncthreads();
    for (int e = ebeg + threadIdx.x; e < eend; e += 512) {
        int c = col[e];
        int b = c >> BSH;
        int r = atomicAdd(&h2[b], 1);
        int slot = st[b] + r;
        if (slot < (b + 1) * ESTRIDE) {  // statistically impossible overflow guard
            unsigned long long rec =
                ((unsigned long long)__float_as_uint(ew[e]) << 32) |
                ((unsigned long long)(unsigned)row[e] << 8) |
                (unsigned)(c & (BSZ - 1));
            part[slot] = rec;
        }
    }
}

// ---- within-bucket counting sort -> padded node-sorted CSR ----
// part region b: [b*ESTRIDE, +cursor[b]). csr region b: [b*CSTRIDE, ...).
// Node runs padded to multiple of 8 with (src=self, w=0). rp = (iters<<26)|ofs
// Counting uses TWO half-block sub-histograms to cut LDS atomic serialization.
__global__ __launch_bounds__(256) void k_sortB(const unsigned long long* __restrict__ part,
                                               const int* __restrict__ cursor,
                                               int2* __restrict__ csr,
                                               unsigned* __restrict__ rp,
                                               float* __restrict__ dinv, int N) {
    __shared__ int cntA[BSZ];
    __shared__ int cntB2[BSZ];
    __shared__ int scn[BSZ];
    __shared__ int cur[BSZ];
    __shared__ float dg[BSZ];
    int b = blockIdx.x;
    int nb0 = b << BSH;
    int nn = min(BSZ, N - nb0);
    int tid = threadIdx.x;
    if (tid < BSZ) { cntA[tid] = 0; cntB2[tid] = 0; dg[tid] = 1.0f; }
    __syncthreads();
    int ebeg = b * ESTRIDE;
    int eend = ebeg + min(cursor[b], ESTRIDE);
    int* myh = (tid & 128) ? cntB2 : cntA;
    for (int e = ebeg + tid; e < eend; e += 256)
        atomicAdd(&myh[(int)(part[e] & (BSZ - 1))], 1);
    __syncthreads();
    int ctot = 0, pc = 0;
    if (tid < BSZ) {
        ctot = cntA[tid] + cntB2[tid];
        pc = min((ctot + 7) & ~7, 504);  // iters<=63
        scn[tid] = pc;
    }
    __syncthreads();
    for (int o = 1; o < BSZ; o <<= 1) {
        int t = 0;
        if (tid >= o && tid < BSZ) t = scn[tid - o];
        __syncthreads();
        if (tid >= o && tid < BSZ) scn[tid] += t;
        __syncthreads();
    }
    int Pb = b * CSTRIDE;
    int pofs = 0;
    if (tid < BSZ) {
        pofs = scn[tid] - pc;
        cur[tid] = pofs;
        if (tid < nn)
            rp[nb0 + tid] = ((unsigned)(pc >> 3) << 26) | (unsigned)(Pb + pofs);
    }
    __syncthreads();
    for (int e = ebeg + tid; e < eend; e += 256) {
        unsigned long long rec = part[e];
        int cl = (int)(rec & (BSZ - 1));
        float w = __uint_as_float((unsigned)(rec >> 32));
        int slot = atomicAdd(&cur[cl], 1);
        csr[Pb + slot] = make_int2((int)((rec >> 8) & 0xFFFFFF), __float_as_int(w));
        atomicAdd(&dg[cl], w);
    }
    __syncthreads();
    if (tid < nn) {
        int c = min(ctot, pc);
        for (int k = c; k < pc; k++)
            csr[Pb + pofs + k] = make_int2(nb0 + tid, 0);
        dinv[nb0 + tid] = rsqrtf(dg[tid]);
    }
}

// ---- conv1 GEMM: Y[i,:] = fp16( dinv[i] * (X_fp32[i,:] @ W) ) ----
template <int K, int H>
__global__ __launch_bounds__(256) void k_gemm_f32(const float* __restrict__ X,
                                                  const float* __restrict__ W,
                                                  const float* __restrict__ dinv,
                                                  __half* __restrict__ Y, int n) {
    __shared__ float Ws[K * H];
    int tid = threadIdx.x;
    for (int i = tid * 4; i < K * H; i += 256 * 4)
        *(float4*)&Ws[i] = *(const float4*)&W[i];
    __syncthreads();

    constexpr int TPR = H / 16;
    constexpr int RPT = 4;
    int c0 = (tid % TPR) * 16;
    int rg = tid / TPR;
    int row0 = blockIdx.x * ((256 / TPR) * RPT) + rg * RPT;
    if (row0 >= n) return;

    float acc[RPT][16];
#pragma unroll
    for (int r = 0; r < RPT; r++)
#pragma unroll
        for (int j = 0; j < 16; j++) acc[r][j] = 0.f;

    int ridx[RPT];
#pragma unroll
    for (int r = 0; r < RPT; r++) ridx[r] = min(row0 + r, n - 1);

    for (int k = 0; k < K; k += 4) {
        float4 xv[RPT];
#pragma unroll
        for (int r = 0; r < RPT; r++)
            xv[r] = *(const float4*)&X[(size_t)ridx[r] * K + k];
#pragma unroll
        for (int kk = 0; kk < 4; kk++) {
            const float* wp = &Ws[(k + kk) * H + c0];
            float w[16];
#pragma unroll
            for (int j = 0; j < 16; j++) w[j] = wp[j];
#pragma unroll
            for (int r = 0; r < RPT; r++) {
                float xs = (&xv[r].x)[kk];
#pragma unroll
                for (int j = 0; j < 16; j++) acc[r][j] += xs * w[j];
            }
        }
    }
#pragma unroll
    for (int r = 0; r < RPT; r++) {
        if (row0 + r < n) {
            float di = dinv[row0 + r];
            __half hb[16];
#pragma unroll
            for (int j = 0; j < 16; j++) hb[j] = __float2half(di * acc[r][j]);
            __half* yr = Y + (size_t)(row0 + r) * H + c0;
            *(uint4*)&yr[0] = *(uint4*)&hb[0];
            *(uint4*)&yr[8] = *(uint4*)&hb[8];
        }
    }
}

// ---- conv2 GEMM: Y[i,:] = fp16( dinv[i] * (X_fp16[i,:] @ W) ) ----
template <int K, int H>
__global__ __launch_bounds__(256) void k_gemm_f16(const __half* __restrict__ X,
                                                  const float* __restrict__ W,
                                                  const float* __restrict__ dinv,
                                                  __half* __restrict__ Y, int n) {
    __shared__ float Ws[K * H];
    int tid = threadIdx.x;
    for (int i = tid * 4; i < K * H; i += 256 * 4)
        *(float4*)&Ws[i] = *(const float4*)&W[i];
    __syncthreads();

    constexpr int TPR = H / 16;
    constexpr int RPT = 4;
    int c0 = (tid % TPR) * 16;
    int rg = tid / TPR;
    int row0 = blockIdx.x * ((256 / TPR) * RPT) + rg * RPT;
    if (row0 >= n) return;

    float acc[RPT][16];
#pragma unroll
    for (int r = 0; r < RPT; r++)
#pragma unroll
        for (int j = 0; j < 16; j++) acc[r][j] = 0.f;

    int ridx[RPT];
#pragma unroll
    for (int r = 0; r < RPT; r++) ridx[r] = min(row0 + r, n - 1);

    for (int k = 0; k < K; k += 8) {
        uint4 raw[RPT];  // 8 halves per row
#pragma unroll
        for (int r = 0; r < RPT; r++)
            raw[r] = *(const uint4*)&X[(size_t)ridx[r] * K + k];
#pragma unroll
        for (int kk = 0; kk < 8; kk++) {
            const float* wp = &Ws[(k + kk) * H + c0];
            float w[16];
#pragma unroll
            for (int j = 0; j < 16; j++) w[j] = wp[j];
#pragma unroll
            for (int r = 0; r < RPT; r++) {
                __half xh = ((const __half*)&raw[r])[kk];
                float xs = __half2float(xh);
#pragma unroll
                for (int j = 0; j < 16; j++) acc[r][j] += xs * w[j];
            }
        }
    }
#pragma unroll
    for (int r = 0; r < RPT; r++) {
        if (row0 + r < n) {
            float di = dinv[row0 + r];
            __half hb[16];
#pragma unroll
            for (int j = 0; j < 16; j++) hb[j] = __float2half(di * acc[r][j]);
            __half* yr = Y + (size_t)(row0 + r) * H + c0;
            *(uint4*)&yr[0] = *(uint4*)&hb[0];
            *(uint4*)&yr[8] = *(uint4*)&hb[8];
        }
    }
}

// ---- aggregation: wave-per-node, paired-lane 32-bit gathers (R8 proven) ----
// lanes 0-31 even edges, 32-63 odd edges; lane owns feature pair 2*(lane&31).
// Hin is fp16 h'=dinv*h. out = fp16(relu(dinv[c]*(h'[c]+sum w*h'[src])+bias))
__global__ __launch_bounds__(256) void k_aggN(const __half* __restrict__ Hin,
                                              const unsigned* __restrict__ rp,
                                              const int2* __restrict__ csr,
                                              const float* __restrict__ dinv,
                                              const float* __restrict__ bias,
                                              __half* __restrict__ Hout, int n) {
    int lane = threadIdx.x & 63;
    int wv = threadIdx.x >> 6;
    int node = blockIdx.x * 4 + wv;
    if (node >= n) return;
    unsigned pk = rp[node];
    int p = (int)(pk & 0x3FFFFFFu);
    int iters = (int)(pk >> 26);
    int fp = lane & 31;                 // feature-pair index
    bool hi = lane >= 32;
    const unsigned* HinU = (const unsigned*)Hin;  // 32 uints per row
    float ax = 0.f, ay = 0.f;
    if (!hi) {  // self term in low half only
        unsigned su = HinU[(size_t)node * 32 + fp];
        float2 sf = __half22float2(*(__half2*)&su);
        ax = sf.x; ay = sf.y;
    }
    for (int it = 0; it < iters; it++, p += 8) {
        int4 m0 = *(const int4*)&csr[p];
        int4 m1 = *(const int4*)&csr[p + 2];
        int4 m2 = *(const int4*)&csr[p + 4];
        int4 m3 = *(const int4*)&csr[p + 6];
        int   s0 = hi ? m0.z : m0.x;
        float w0 = __int_as_float(hi ? m0.w : m0.y);
        int   s1 = hi ? m1.z : m1.x;
        float w1 = __int_as_float(hi ? m1.w : m1.y);
        int   s2 = hi ? m2.z : m2.x;
        float w2 = __int_as_float(hi ? m2.w : m2.y);
        int   s3 = hi ? m3.z : m3.x;
        float w3 = __int_as_float(hi ? m3.w : m3.y);
        unsigned u0 = HinU[(size_t)s0 * 32 + fp];
        unsigned u1 = HinU[(size_t)s1 * 32 + fp];
        unsigned u2 = HinU[(size_t)s2 * 32 + fp];
        unsigned u3 = HinU[(size_t)s3 * 32 + fp];
        float2 f0 = __half22float2(*(__half2*)&u0);
        float2 f1 = __half22float2(*(__half2*)&u1);
        float2 f2 = __half22float2(*(__half2*)&u2);
        float2 f3 = __half22float2(*(__half2*)&u3);
        ax += w0 * f0.x; ay += w0 * f0.y;
        ax += w1 * f1.x; ay += w1 * f1.y;
        ax += w2 * f2.x; ay += w2 * f2.y;
        ax += w3 * f3.x; ay += w3 * f3.y;
    }
    // merge odd-edge half into even half
    ax += __shfl_xor(ax, 32, 64);
    ay += __shfl_xor(ay, 32, 64);
    if (!hi) {
        float di = dinv[node];
        float vx = di * ax + bias[2 * fp];
        float vy = di * ay + bias[2 * fp + 1];
        vx = vx > 0.f ? vx : 0.f;
        vy = vy > 0.f ? vy : 0.f;
        __half2 o = __floats2half2_rn(vx, vy);
        *(__half2*)&Hout[(size_t)node * DIMH + 2 * fp] = o;
    }
}

// ---- mean-pool (b sorted, fp16 in): per-wave chunk, flush on change ----
__global__ __launch_bounds__(256) void k_pool(const __half* __restrict__ Hin,
                                              const int* __restrict__ b,
                                              float* __restrict__ sums,
                                              float* __restrict__ cntG, int n) {
    const int CHUNK = 64;
    int lane = threadIdx.x & 63;
    int wave = threadIdx.x >> 6;
    int start = (blockIdx.x * 4 + wave) * CHUNK;
    if (start >= n) return;
    int end = min(start + CHUNK, n);
    float acc = 0.f;
    int g_cur = b[start];
    int cnt_local = 0;
    for (int i = start; i < end; i++) {
        int g = b[i];
        if (g != g_cur) {
            atomicAdd(&sums[g_cur * DIMH + lane], acc);
            if (lane == 0) atomicAdd(&cntG[g_cur], (float)cnt_local);
            acc = 0.f;
            cnt_local = 0;
            g_cur = g;
        }
        acc += __half2float(Hin[(size_t)i * DIMH + lane]);
        cnt_local++;
    }
    atomicAdd(&sums[g_cur * DIMH + lane], acc);
    if (lane == 0) atomicAdd(&cntG[g_cur], (float)cnt_local);
}

// ---- head MLP ----
__global__ __launch_bounds__(64) void k_mlp(const float* __restrict__ sums,
                                            const float* __restrict__ cntG,
                                            const float* __restrict__ Wm1,
                                            const float* __restrict__ bm1,
                                            const float* __restrict__ Wm2,
                                            const float* __restrict__ bm2,
                                            float* __restrict__ out, int G) {
    int g = threadIdx.x;
    if (g >= G) return;
    float c = cntG[g];
    float inv = 1.f / (c > 1.f ? c : 1.f);
    float pooled[DIMH];
#pragma unroll
    for (int k = 0; k < DIMH; k++) pooled[k] = sums[g * DIMH + k] * inv;
    float o = 0.f;
    for (int j = 0; j < 32; j++) {
        float t = bm1[j];
#pragma unroll
        for (int k = 0; k < DIMH; k++) t += pooled[k] * Wm1[k * 32 + j];
        t = t > 0.f ? t : 0.f;
        o += t * Wm2[j];
    }
    out[g] = o + bm2[0];
}

// ============================== launch ==============================

extern "C" void kernel_launch(void* const* d_in, const int* in_sizes, int n_in,
                              void* d_out, int out_size, void* d_ws, size_t ws_size,
                              hipStream_t stream) {
    const float* x   = (const float*)d_in[0];
    const int*   ei  = (const int*)d_in[1];
    const float* ew  = (const float*)d_in[2];
    const int*   bvec= (const int*)d_in[3];
    const float* W1  = (const float*)d_in[4];
    const float* b1  = (const float*)d_in[5];
    const float* W2  = (const float*)d_in[6];
    const float* b2  = (const float*)d_in[7];
    const float* Wm1 = (const float*)d_in[8];
    const float* bm1 = (const float*)d_in[9];
    const float* Wm2 = (const float*)d_in[10];
    const float* bm2 = (const float*)d_in[11];
    float* out = (float*)d_out;

    const int E = in_sizes[2];
    const int N = in_sizes[3];
    const int G = out_size;
    const int* row = ei;
    const int* col = ei + E;
    const int nbuck = (N + BSZ - 1) >> BSH;   // 782 for N=100000

    char* p = (char*)d_ws;
    auto alloc = [&](size_t bytes) {
        void* r = (void*)p;
        p += (bytes + 255) & ~(size_t)255;
        return r;
    };

    unsigned long long* part = (unsigned long long*)alloc((size_t)nbuck * ESTRIDE * 8);
    int2*  csr    = (int2*)alloc((size_t)nbuck * CSTRIDE * 8);
    unsigned* rp  = (unsigned*)alloc((size_t)N * 4);
    float* dinv   = (float*)alloc((size_t)N * 4);
    __half* hA    = (__half*)alloc((size_t)N * DIMH * 2);
    __half* hB    = (__half*)alloc((size_t)N * DIMH * 2);
    // zero region: [cursor | sums | cntG] -> one memset
    int zeroInts  = nbuck + G * DIMH + G;
    int* cursor   = (int*)alloc((size_t)zeroInts * 4);
    float* sums   = (float*)(cursor + nbuck);
    float* cntG   = sums + G * DIMH;

    hipMemsetAsync(cursor, 0, (size_t)zeroInts * 4, stream);

    const int PB = (E + EPB - 1) / EPB;       // 196 partition blocks

    // 1. partition + sort -> padded CSR, packed row_ptr, dinv
    k_part<<<PB, 512, 0, stream>>>(row, col, ew, cursor, part, E, nbuck);
    k_sortB<<<nbuck, 256, 0, stream>>>(part, cursor, csr, rp, dinv, N);

    // 2. conv1
    k_gemm_f32<128, DIMH><<<(N + 255) / 256, 256, 0, stream>>>(x, W1, dinv, hA, N);
    k_aggN<<<(N + 3) / 4, 256, 0, stream>>>(hA, rp, csr, dinv, b1, hB, N);

    // 3. conv2
    k_gemm_f16<DIMH, DIMH><<<(N + 255) / 256, 256, 0, stream>>>(hB, W2, dinv, hA, N);
    k_aggN<<<(N + 3) / 4, 256, 0, stream>>>(hA, rp, csr, dinv, b2, hB, N);

    // 4. pool + head
    k_pool<<<(N + 255) / 256, 256, 0, stream>>>(hB, bvec, sums, cntG, N);
    k_mlp<<<1, 64, 0, stream>>>(sums, cntG, Wm1, bm1, Wm2, bm2, out, G);
}

// Round 12
// 343.774 us; speedup vs baseline: 1.0560x; 1.0560x over previous
//
#include <hip/hip_runtime.h>
#include <hip/hip_bf16.h>
#include <hip/hip_fp16.h>

// GCN: gcn_norm -> conv1(relu) -> conv2(relu) -> mean-pool -> MLP head.
// R12: conv2 GEMM fused into agg1's epilogue (k_agg1f): after the gather
// merge, the wave's h row goes through a per-wave LDS broadcast and a
// 64x64 matvec against LDS-staged W2, emitting the conv2 gather table
// directly (kills k_gemm_f16 + a 25.6MB round-trip). Build reverted to
// R9-best (EPB 4096, single-hist sortB). Agg gather loop untouched
// (~55us line-service floor, confirmed R8/R9/R11).
// fp16 feature tables, fp32 accumulation everywhere.

#define DIMH 64
#define BSH 7                 // 128 nodes per bucket
#define BSZ 128
#define NBUCK_MAX 1024
#define EPB 4096              // edges per partition block (391 blocks)
#define ESTRIDE 3072          // part region per bucket (mean fill ~2046)
#define CSTRIDE 4096          // padded csr region per bucket (max 3968)

// ---- scatter edges into strided bucket regions (LDS 2-pass, 1 global
//      atomic per (block,bucket); cursor zero-based, memset-cleared) ----
// record: [63:32]=w fp32 bits, [31:8]=src, [7:0]=c_local
__global__ __launch_bounds__(512) void k_part(const int* __restrict__ row,
                                              const int* __restrict__ col,
                                              const float* __restrict__ ew,
                                              int* __restrict__ cursor,
                                              unsigned long long* __restrict__ part,
                                              int E, int nbuck) {
    __shared__ int h[NBUCK_MAX];
    __shared__ int h2[NBUCK_MAX];
    __shared__ int st[NBUCK_MAX];
    for (int i = threadIdx.x; i < nbuck; i += 512) { h[i] = 0; h2[i] = 0; }
    __syncthreads();
    int ebeg = blockIdx.x * EPB;
    int eend = min(ebeg + EPB, E);
    for (int e = ebeg + threadIdx.x; e < eend; e += 512)
        atomicAdd(&h[col[e] >> BSH], 1);
    __syncthreads();
    for (int i = threadIdx.x; i < nbuck; i += 512) {
        int c = h[i];
        st[i] = c ? i * ESTRIDE + atomicAdd(&cursor[i], c) : 0;
    }
    __syncthreads();
    for (int e = ebeg + threadIdx.x; e < eend; e += 512) {
        int c = col[e];
        int b = c >> BSH;
        int r = atomicAdd(&h2[b], 1);
        int slot = st[b] + r;
        if (slot < (b + 1) * ESTRIDE) {  // statistically impossible overflow guard
            unsigned long long rec =
                ((unsigned long long)__float_as_uint(ew[e]) << 32) |
                ((unsigned long long)(unsigned)row[e] << 8) |
                (unsigned)(c & (BSZ - 1));
            part[slot] = rec;
        }
    }
}

// ---- within-bucket counting sort -> padded node-sorted CSR ----
// part region b: [b*ESTRIDE, +cursor[b]). csr region b: [b*CSTRIDE, ...).
// Node runs padded to multiple of 8 with (src=self, w=0). rp = (iters<<26)|ofs
__global__ __launch_bounds__(256) void k_sortB(const unsigned long long* __restrict__ part,
                                               const int* __restrict__ cursor,
                                               int2* __restrict__ csr,
                                               unsigned* __restrict__ rp,
                                               float* __restrict__ dinv, int N) {
    __shared__ int cnt[BSZ];
    __shared__ int scn[BSZ];
    __shared__ int cur[BSZ];
    __shared__ float dg[BSZ];
    int b = blockIdx.x;
    int nb0 = b << BSH;
    int nn = min(BSZ, N - nb0);
    int tid = threadIdx.x;
    if (tid < BSZ) { cnt[tid] = 0; dg[tid] = 1.0f; }  // self-loop weight 1
    __syncthreads();
    int ebeg = b * ESTRIDE;
    int eend = ebeg + min(cursor[b], ESTRIDE);
    for (int e = ebeg + tid; e < eend; e += 256)
        atomicAdd(&cnt[(int)(part[e] & (BSZ - 1))], 1);
    __syncthreads();
    int pc = 0;
    if (tid < BSZ) pc = min((cnt[tid] + 7) & ~7, 504);  // iters<=63
    if (tid < BSZ) scn[tid] = pc;
    __syncthreads();
    for (int o = 1; o < BSZ; o <<= 1) {
        int t = 0;
        if (tid >= o && tid < BSZ) t = scn[tid - o];
        __syncthreads();
        if (tid >= o && tid < BSZ) scn[tid] += t;
        __syncthreads();
    }
    int Pb = b * CSTRIDE;
    int pofs = 0;
    if (tid < BSZ) {
        pofs = scn[tid] - pc;
        cur[tid] = pofs;
        if (tid < nn)
            rp[nb0 + tid] = ((unsigned)(pc >> 3) << 26) | (unsigned)(Pb + pofs);
    }
    __syncthreads();
    for (int e = ebeg + tid; e < eend; e += 256) {
        unsigned long long rec = part[e];
        int cl = (int)(rec & (BSZ - 1));
        float w = __uint_as_float((unsigned)(rec >> 32));
        int slot = atomicAdd(&cur[cl], 1);
        csr[Pb + slot] = make_int2((int)((rec >> 8) & 0xFFFFFF), __float_as_int(w));
        atomicAdd(&dg[cl], w);
    }
    __syncthreads();
    if (tid < nn) {
        int c = min(cnt[tid], pc);
        for (int k = c; k < pc; k++)
            csr[Pb + pofs + k] = make_int2(nb0 + tid, 0);
        dinv[nb0 + tid] = rsqrtf(dg[tid]);
    }
}

// ---- conv1 GEMM: Y[i,:] = fp16( dinv[i] * (X_fp32[i,:] @ W) ) ----
template <int K, int H>
__global__ __launch_bounds__(256) void k_gemm_f32(const float* __restrict__ X,
                                                  const float* __restrict__ W,
                                                  const float* __restrict__ dinv,
                                                  __half* __restrict__ Y, int n) {
    __shared__ float Ws[K * H];
    int tid = threadIdx.x;
    for (int i = tid * 4; i < K * H; i += 256 * 4)
        *(float4*)&Ws[i] = *(const float4*)&W[i];
    __syncthreads();

    constexpr int TPR = H / 16;
    constexpr int RPT = 4;
    int c0 = (tid % TPR) * 16;
    int rg = tid / TPR;
    int row0 = blockIdx.x * ((256 / TPR) * RPT) + rg * RPT;
    if (row0 >= n) return;

    float acc[RPT][16];
#pragma unroll
    for (int r = 0; r < RPT; r++)
#pragma unroll
        for (int j = 0; j < 16; j++) acc[r][j] = 0.f;

    int ridx[RPT];
#pragma unroll
    for (int r = 0; r < RPT; r++) ridx[r] = min(row0 + r, n - 1);

    for (int k = 0; k < K; k += 4) {
        float4 xv[RPT];
#pragma unroll
        for (int r = 0; r < RPT; r++)
            xv[r] = *(const float4*)&X[(size_t)ridx[r] * K + k];
#pragma unroll
        for (int kk = 0; kk < 4; kk++) {
            const float* wp = &Ws[(k + kk) * H + c0];
            float w[16];
#pragma unroll
            for (int j = 0; j < 16; j++) w[j] = wp[j];
#pragma unroll
            for (int r = 0; r < RPT; r++) {
                float xs = (&xv[r].x)[kk];
#pragma unroll
                for (int j = 0; j < 16; j++) acc[r][j] += xs * w[j];
            }
        }
    }
#pragma unroll
    for (int r = 0; r < RPT; r++) {
        if (row0 + r < n) {
            float di = dinv[row0 + r];
            __half hb[16];
#pragma unroll
            for (int j = 0; j < 16; j++) hb[j] = __float2half(di * acc[r][j]);
            __half* yr = Y + (size_t)(row0 + r) * H + c0;
            *(uint4*)&yr[0] = *(uint4*)&hb[0];
            *(uint4*)&yr[8] = *(uint4*)&hb[8];
        }
    }
}

// ---- agg1 + fused conv2 GEMM ----
// Gather phase identical to k_aggN (paired-lane 32-bit gathers on fp16
// table T1 = dinv*(x@W1)). Epilogue: h = relu(dinv*acc + b1) -> per-wave
// LDS broadcast -> 64x64 matvec vs LDS-staged W2 -> T2 = fp16(dinv*(h@W2)).
// Grid-stride (4096 blocks) to amortize the 16KB W2 staging.
__global__ __launch_bounds__(256) void k_agg1f(const __half* __restrict__ Hin,
                                               const unsigned* __restrict__ rp,
                                               const int2* __restrict__ csr,
                                               const float* __restrict__ dinv,
                                               const float* __restrict__ bias,
                                               const float* __restrict__ W2,
                                               __half* __restrict__ T2, int n) {
    __shared__ float W2s[DIMH * DIMH];   // 16 KB
    __shared__ unsigned hbuf[4][32];     // per-wave h row (64 halves)
    int tid = threadIdx.x;
    for (int i = tid * 4; i < DIMH * DIMH; i += 256 * 4)
        *(float4*)&W2s[i] = *(const float4*)&W2[i];
    __syncthreads();

    int lane = tid & 63;
    int wv = tid >> 6;
    int fp = lane & 31;
    bool hi = lane >= 32;
    const unsigned* HinU = (const unsigned*)Hin;  // 32 uints per row
    int ngroups = (n + 3) >> 2;

    for (int grp = blockIdx.x; grp < ngroups; grp += gridDim.x) {
        int node = grp * 4 + wv;
        if (node >= n) continue;
        unsigned pk = rp[node];
        int p = (int)(pk & 0x3FFFFFFu);
        int iters = (int)(pk >> 26);
        float ax = 0.f, ay = 0.f;
        if (!hi) {  // self term in low half only
            unsigned su = HinU[(size_t)node * 32 + fp];
            float2 sf = __half22float2(*(__half2*)&su);
            ax = sf.x; ay = sf.y;
        }
        for (int it = 0; it < iters; it++, p += 8) {
            int4 m0 = *(const int4*)&csr[p];
            int4 m1 = *(const int4*)&csr[p + 2];
            int4 m2 = *(const int4*)&csr[p + 4];
            int4 m3 = *(const int4*)&csr[p + 6];
            int   s0 = hi ? m0.z : m0.x;
            float w0 = __int_as_float(hi ? m0.w : m0.y);
            int   s1 = hi ? m1.z : m1.x;
            float w1 = __int_as_float(hi ? m1.w : m1.y);
            int   s2 = hi ? m2.z : m2.x;
            float w2 = __int_as_float(hi ? m2.w : m2.y);
            int   s3 = hi ? m3.z : m3.x;
            float w3 = __int_as_float(hi ? m3.w : m3.y);
            unsigned u0 = HinU[(size_t)s0 * 32 + fp];
            unsigned u1 = HinU[(size_t)s1 * 32 + fp];
            unsigned u2 = HinU[(size_t)s2 * 32 + fp];
            unsigned u3 = HinU[(size_t)s3 * 32 + fp];
            float2 f0 = __half22float2(*(__half2*)&u0);
            float2 f1 = __half22float2(*(__half2*)&u1);
            float2 f2 = __half22float2(*(__half2*)&u2);
            float2 f3 = __half22float2(*(__half2*)&u3);
            ax += w0 * f0.x; ay += w0 * f0.y;
            ax += w1 * f1.x; ay += w1 * f1.y;
            ax += w2 * f2.x; ay += w2 * f2.y;
            ax += w3 * f3.x; ay += w3 * f3.y;
        }
        ax += __shfl_xor(ax, 32, 64);
        ay += __shfl_xor(ay, 32, 64);
        float di = dinv[node];
        if (!hi) {
            float vx = di * ax + bias[2 * fp];
            float vy = di * ay + bias[2 * fp + 1];
            vx = vx > 0.f ? vx : 0.f;
            vy = vy > 0.f ? vy : 0.f;
            __half2 hh = __floats2half2_rn(vx, vy);
            hbuf[wv][fp] = *(unsigned*)&hh;   // fp16-quantized h (matches old path)
        }
        // same-wave LDS write->read; compiler orders via lgkmcnt
        float acc2 = 0.f;
        const unsigned* hb = hbuf[wv];
#pragma unroll
        for (int k8 = 0; k8 < 8; k8++) {
            uint4 hc = *(const uint4*)&hb[k8 * 4];   // broadcast read
            float2 g0 = __half22float2(*(__half2*)&hc.x);
            float2 g1 = __half22float2(*(__half2*)&hc.y);
            float2 g2 = __half22float2(*(__half2*)&hc.z);
            float2 g3 = __half22float2(*(__half2*)&hc.w);
            const float* wc = &W2s[(k8 * 8) * DIMH + lane];
            acc2 += g0.x * wc[0 * DIMH] + g0.y * wc[1 * DIMH]
                  + g1.x * wc[2 * DIMH] + g1.y * wc[3 * DIMH]
                  + g2.x * wc[4 * DIMH] + g2.y * wc[5 * DIMH]
                  + g3.x * wc[6 * DIMH] + g3.y * wc[7 * DIMH];
        }
        T2[(size_t)node * DIMH + lane] = __float2half(di * acc2);
    }
}

// ---- agg2: wave-per-node, paired-lane 32-bit gathers (R8/R11 proven) ----
// Hin is fp16 T2 = dinv*(h@W2). out = fp16(relu(dinv[c]*(T2[c]+sum w*T2[src])+b2))
__global__ __launch_bounds__(256) void k_aggN(const __half* __restrict__ Hin,
                                              const unsigned* __restrict__ rp,
                                              const int2* __restrict__ csr,
                                              const float* __restrict__ dinv,
                                              const float* __restrict__ bias,
                                              __half* __restrict__ Hout, int n) {
    int lane = threadIdx.x & 63;
    int wv = threadIdx.x >> 6;
    int node = blockIdx.x * 4 + wv;
    if (node >= n) return;
    unsigned pk = rp[node];
    int p = (int)(pk & 0x3FFFFFFu);
    int iters = (int)(pk >> 26);
    int fp = lane & 31;
    bool hi = lane >= 32;
    const unsigned* HinU = (const unsigned*)Hin;
    float ax = 0.f, ay = 0.f;
    if (!hi) {
        unsigned su = HinU[(size_t)node * 32 + fp];
        float2 sf = __half22float2(*(__half2*)&su);
        ax = sf.x; ay = sf.y;
    }
    for (int it = 0; it < iters; it++, p += 8) {
        int4 m0 = *(const int4*)&csr[p];
        int4 m1 = *(const int4*)&csr[p + 2];
        int4 m2 = *(const int4*)&csr[p + 4];
        int4 m3 = *(const int4*)&csr[p + 6];
        int   s0 = hi ? m0.z : m0.x;
        float w0 = __int_as_float(hi ? m0.w : m0.y);
        int   s1 = hi ? m1.z : m1.x;
        float w1 = __int_as_float(hi ? m1.w : m1.y);
        int   s2 = hi ? m2.z : m2.x;
        float w2 = __int_as_float(hi ? m2.w : m2.y);
        int   s3 = hi ? m3.z : m3.x;
        float w3 = __int_as_float(hi ? m3.w : m3.y);
        unsigned u0 = HinU[(size_t)s0 * 32 + fp];
        unsigned u1 = HinU[(size_t)s1 * 32 + fp];
        unsigned u2 = HinU[(size_t)s2 * 32 + fp];
        unsigned u3 = HinU[(size_t)s3 * 32 + fp];
        float2 f0 = __half22float2(*(__half2*)&u0);
        float2 f1 = __half22float2(*(__half2*)&u1);
        float2 f2 = __half22float2(*(__half2*)&u2);
        float2 f3 = __half22float2(*(__half2*)&u3);
        ax += w0 * f0.x; ay += w0 * f0.y;
        ax += w1 * f1.x; ay += w1 * f1.y;
        ax += w2 * f2.x; ay += w2 * f2.y;
        ax += w3 * f3.x; ay += w3 * f3.y;
    }
    ax += __shfl_xor(ax, 32, 64);
    ay += __shfl_xor(ay, 32, 64);
    if (!hi) {
        float di = dinv[node];
        float vx = di * ax + bias[2 * fp];
        float vy = di * ay + bias[2 * fp + 1];
        vx = vx > 0.f ? vx : 0.f;
        vy = vy > 0.f ? vy : 0.f;
        __half2 o = __floats2half2_rn(vx, vy);
        *(__half2*)&Hout[(size_t)node * DIMH + 2 * fp] = o;
    }
}

// ---- mean-pool (b sorted, fp16 in): per-wave chunk, flush on change ----
__global__ __launch_bounds__(256) void k_pool(const __half* __restrict__ Hin,
                                              const int* __restrict__ b,
                                              float* __restrict__ sums,
                                              float* __restrict__ cntG, int n) {
    const int CHUNK = 64;
    int lane = threadIdx.x & 63;
    int wave = threadIdx.x >> 6;
    int start = (blockIdx.x * 4 + wave) * CHUNK;
    if (start >= n) return;
    int end = min(start + CHUNK, n);
    float acc = 0.f;
    int g_cur = b[start];
    int cnt_local = 0;
    for (int i = start; i < end; i++) {
        int g = b[i];
        if (g != g_cur) {
            atomicAdd(&sums[g_cur * DIMH + lane], acc);
            if (lane == 0) atomicAdd(&cntG[g_cur], (float)cnt_local);
            acc = 0.f;
            cnt_local = 0;
            g_cur = g;
        }
        acc += __half2float(Hin[(size_t)i * DIMH + lane]);
        cnt_local++;
    }
    atomicAdd(&sums[g_cur * DIMH + lane], acc);
    if (lane == 0) atomicAdd(&cntG[g_cur], (float)cnt_local);
}

// ---- head MLP ----
__global__ __launch_bounds__(64) void k_mlp(const float* __restrict__ sums,
                                            const float* __restrict__ cntG,
                                            const float* __restrict__ Wm1,
                                            const float* __restrict__ bm1,
                                            const float* __restrict__ Wm2,
                                            const float* __restrict__ bm2,
                                            float* __restrict__ out, int G) {
    int g = threadIdx.x;
    if (g >= G) return;
    float c = cntG[g];
    float inv = 1.f / (c > 1.f ? c : 1.f);
    float pooled[DIMH];
#pragma unroll
    for (int k = 0; k < DIMH; k++) pooled[k] = sums[g * DIMH + k] * inv;
    float o = 0.f;
    for (int j = 0; j < 32; j++) {
        float t = bm1[j];
#pragma unroll
        for (int k = 0; k < DIMH; k++) t += pooled[k] * Wm1[k * 32 + j];
        t = t > 0.f ? t : 0.f;
        o += t * Wm2[j];
    }
    out[g] = o + bm2[0];
}

// ============================== launch ==============================

extern "C" void kernel_launch(void* const* d_in, const int* in_sizes, int n_in,
                              void* d_out, int out_size, void* d_ws, size_t ws_size,
                              hipStream_t stream) {
    const float* x   = (const float*)d_in[0];
    const int*   ei  = (const int*)d_in[1];
    const float* ew  = (const float*)d_in[2];
    const int*   bvec= (const int*)d_in[3];
    const float* W1  = (const float*)d_in[4];
    const float* b1  = (const float*)d_in[5];
    const float* W2  = (const float*)d_in[6];
    const float* b2  = (const float*)d_in[7];
    const float* Wm1 = (const float*)d_in[8];
    const float* bm1 = (const float*)d_in[9];
    const float* Wm2 = (const float*)d_in[10];
    const float* bm2 = (const float*)d_in[11];
    float* out = (float*)d_out;

    const int E = in_sizes[2];
    const int N = in_sizes[3];
    const int G = out_size;
    const int* row = ei;
    const int* col = ei + E;
    const int nbuck = (N + BSZ - 1) >> BSH;   // 782 for N=100000

    char* p = (char*)d_ws;
    auto alloc = [&](size_t bytes) {
        void* r = (void*)p;
        p += (bytes + 255) & ~(size_t)255;
        return r;
    };

    unsigned long long* part = (unsigned long long*)alloc((size_t)nbuck * ESTRIDE * 8);
    int2*  csr    = (int2*)alloc((size_t)nbuck * CSTRIDE * 8);
    unsigned* rp  = (unsigned*)alloc((size_t)N * 4);
    float* dinv   = (float*)alloc((size_t)N * 4);
    __half* hA    = (__half*)alloc((size_t)N * DIMH * 2);  // T1, then conv2 out
    __half* hB    = (__half*)alloc((size_t)N * DIMH * 2);  // T2
    // zero region: [cursor | sums | cntG] -> one memset
    int zeroInts  = nbuck + G * DIMH + G;
    int* cursor   = (int*)alloc((size_t)zeroInts * 4);
    float* sums   = (float*)(cursor + nbuck);
    float* cntG   = sums + G * DIMH;

    hipMemsetAsync(cursor, 0, (size_t)zeroInts * 4, stream);

    const int PB = (E + EPB - 1) / EPB;       // 391 partition blocks

    // 1. partition + sort -> padded CSR, packed row_ptr, dinv
    k_part<<<PB, 512, 0, stream>>>(row, col, ew, cursor, part, E, nbuck);
    k_sortB<<<nbuck, 256, 0, stream>>>(part, cursor, csr, rp, dinv, N);

    // 2. conv1 GEMM -> T1 (hA)
    k_gemm_f32<128, DIMH><<<(N + 255) / 256, 256, 0, stream>>>(x, W1, dinv, hA, N);

    // 3. agg1 + fused conv2 GEMM -> T2 (hB)
    k_agg1f<<<4096, 256, 0, stream>>>(hA, rp, csr, dinv, b1, W2, hB, N);

    // 4. agg2 -> conv2 output (hA, T1 dead)
    k_aggN<<<(N + 3) / 4, 256, 0, stream>>>(hB, rp, csr, dinv, b2, hA, N);

    // 5. pool + head
    k_pool<<<(N + 255) / 256, 256, 0, stream>>>(hA, bvec, sums, cntG, N);
    k_mlp<<<1, 64, 0, stream>>>(sums, cntG, Wm1, bm1, Wm2, bm2, out, G);
}

// Round 13
// 326.703 us; speedup vs baseline: 1.1111x; 1.0523x over previous
//
#include <hip/hip_runtime.h>
#include <hip/hip_bf16.h>
#include <hip/hip_fp16.h>

// GCN: gcn_norm -> conv1(relu) -> conv2(relu) -> mean-pool -> MLP head.
// R13: conv1 GEMM moved to MFMA (16x16x32 f16, fp32 accum): per-wave
// 16-node tile, W1 B-frags loaded once from LDS, x converted fp32->fp16
// in-register. Everything else identical to R12 (agg1f fused conv2,
// aggs at their ~55us line-service floor, R9-best build).

#define DIMH 64
#define BSH 7                 // 128 nodes per bucket
#define BSZ 128
#define NBUCK_MAX 1024
#define EPB 4096              // edges per partition block (391 blocks)
#define ESTRIDE 3072          // part region per bucket (mean fill ~2046)
#define CSTRIDE 4096          // padded csr region per bucket (max 3968)

typedef _Float16 v8h __attribute__((ext_vector_type(8)));
typedef float v4f __attribute__((ext_vector_type(4)));

// ---- scatter edges into strided bucket regions ----
// record: [63:32]=w fp32 bits, [31:8]=src, [7:0]=c_local
__global__ __launch_bounds__(512) void k_part(const int* __restrict__ row,
                                              const int* __restrict__ col,
                                              const float* __restrict__ ew,
                                              int* __restrict__ cursor,
                                              unsigned long long* __restrict__ part,
                                              int E, int nbuck) {
    __shared__ int h[NBUCK_MAX];
    __shared__ int h2[NBUCK_MAX];
    __shared__ int st[NBUCK_MAX];
    for (int i = threadIdx.x; i < nbuck; i += 512) { h[i] = 0; h2[i] = 0; }
    __syncthreads();
    int ebeg = blockIdx.x * EPB;
    int eend = min(ebeg + EPB, E);
    for (int e = ebeg + threadIdx.x; e < eend; e += 512)
        atomicAdd(&h[col[e] >> BSH], 1);
    __syncthreads();
    for (int i = threadIdx.x; i < nbuck; i += 512) {
        int c = h[i];
        st[i] = c ? i * ESTRIDE + atomicAdd(&cursor[i], c) : 0;
    }
    __syncthreads();
    for (int e = ebeg + threadIdx.x; e < eend; e += 512) {
        int c = col[e];
        int b = c >> BSH;
        int r = atomicAdd(&h2[b], 1);
        int slot = st[b] + r;
        if (slot < (b + 1) * ESTRIDE) {
            unsigned long long rec =
                ((unsigned long long)__float_as_uint(ew[e]) << 32) |
                ((unsigned long long)(unsigned)row[e] << 8) |
                (unsigned)(c & (BSZ - 1));
            part[slot] = rec;
        }
    }
}

// ---- within-bucket counting sort -> padded node-sorted CSR ----
__global__ __launch_bounds__(256) void k_sortB(const unsigned long long* __restrict__ part,
                                               const int* __restrict__ cursor,
                                               int2* __restrict__ csr,
                                               unsigned* __restrict__ rp,
                                               float* __restrict__ dinv, int N) {
    __shared__ int cnt[BSZ];
    __shared__ int scn[BSZ];
    __shared__ int cur[BSZ];
    __shared__ float dg[BSZ];
    int b = blockIdx.x;
    int nb0 = b << BSH;
    int nn = min(BSZ, N - nb0);
    int tid = threadIdx.x;
    if (tid < BSZ) { cnt[tid] = 0; dg[tid] = 1.0f; }  // self-loop weight 1
    __syncthreads();
    int ebeg = b * ESTRIDE;
    int eend = ebeg + min(cursor[b], ESTRIDE);
    for (int e = ebeg + tid; e < eend; e += 256)
        atomicAdd(&cnt[(int)(part[e] & (BSZ - 1))], 1);
    __syncthreads();
    int pc = 0;
    if (tid < BSZ) pc = min((cnt[tid] + 7) & ~7, 504);  // iters<=63
    if (tid < BSZ) scn[tid] = pc;
    __syncthreads();
    for (int o = 1; o < BSZ; o <<= 1) {
        int t = 0;
        if (tid >= o && tid < BSZ) t = scn[tid - o];
        __syncthreads();
        if (tid >= o && tid < BSZ) scn[tid] += t;
        __syncthreads();
    }
    int Pb = b * CSTRIDE;
    int pofs = 0;
    if (tid < BSZ) {
        pofs = scn[tid] - pc;
        cur[tid] = pofs;
        if (tid < nn)
            rp[nb0 + tid] = ((unsigned)(pc >> 3) << 26) | (unsigned)(Pb + pofs);
    }
    __syncthreads();
    for (int e = ebeg + tid; e < eend; e += 256) {
        unsigned long long rec = part[e];
        int cl = (int)(rec & (BSZ - 1));
        float w = __uint_as_float((unsigned)(rec >> 32));
        int slot = atomicAdd(&cur[cl], 1);
        csr[Pb + slot] = make_int2((int)((rec >> 8) & 0xFFFFFF), __float_as_int(w));
        atomicAdd(&dg[cl], w);
    }
    __syncthreads();
    if (tid < nn) {
        int c = min(cnt[tid], pc);
        for (int k = c; k < pc; k++)
            csr[Pb + pofs + k] = make_int2(nb0 + tid, 0);
        dinv[nb0 + tid] = rsqrtf(dg[tid]);
    }
}

// ---- conv1 GEMM via MFMA: Y[i,:] = fp16( dinv[i] * (X[i,:] @ W) ) ----
// K=128, H=64. One 16-node tile per wave; 4 waves/block; W staged in LDS
// as fp16, B-frags loaded once and reused. fp32 accumulation (AGPR).
__global__ __launch_bounds__(256) void k_gemm_mfma(const float* __restrict__ X,
                                                   const float* __restrict__ W,
                                                   const float* __restrict__ dinv,
                                                   __half* __restrict__ Y, int n) {
    __shared__ _Float16 Wh[128 * 64];   // 16 KB
    int tid = threadIdx.x;
    for (int i = tid * 4; i < 128 * 64; i += 256 * 4) {
        float4 w = *(const float4*)&W[i];
        Wh[i]     = (_Float16)w.x;
        Wh[i + 1] = (_Float16)w.y;
        Wh[i + 2] = (_Float16)w.z;
        Wh[i + 3] = (_Float16)w.w;
    }
    __syncthreads();

    int wv = tid >> 6;
    int lane = tid & 63;
    int m = lane & 15;        // A row / D col index
    int quad = lane >> 4;     // k-chunk / D row-group index
    int tile = blockIdx.x * 4 + wv;
    int ntiles = (n + 15) >> 4;
    if (tile >= ntiles) return;

    // B fragments: B[n=lane&15][k=quad*8+j], k = s*32 + quad*8 + j
    v8h bf[4][4];
#pragma unroll
    for (int nt = 0; nt < 4; nt++)
#pragma unroll
        for (int s = 0; s < 4; s++)
#pragma unroll
            for (int j = 0; j < 8; j++)
                bf[nt][s][j] = Wh[(s * 32 + quad * 8 + j) * 64 + nt * 16 + m];

    v4f acc[4];
#pragma unroll
    for (int nt = 0; nt < 4; nt++) acc[nt] = (v4f){0.f, 0.f, 0.f, 0.f};

    int row = min(tile * 16 + m, n - 1);
    const float* xr = X + (size_t)row * 128;
#pragma unroll
    for (int s = 0; s < 4; s++) {
        float4 lo = *(const float4*)&xr[s * 32 + quad * 8];
        float4 hi = *(const float4*)&xr[s * 32 + quad * 8 + 4];
        v8h af;
        af[0] = (_Float16)lo.x; af[1] = (_Float16)lo.y;
        af[2] = (_Float16)lo.z; af[3] = (_Float16)lo.w;
        af[4] = (_Float16)hi.x; af[5] = (_Float16)hi.y;
        af[6] = (_Float16)hi.z; af[7] = (_Float16)hi.w;
#pragma unroll
        for (int nt = 0; nt < 4; nt++)
            acc[nt] = __builtin_amdgcn_mfma_f32_16x16x32_f16(af, bf[nt][s], acc[nt], 0, 0, 0);
    }

    // D layout: col = lane&15 (= m), row = quad*4 + r
#pragma unroll
    for (int r = 0; r < 4; r++) {
        int node = tile * 16 + quad * 4 + r;
        if (node < n) {
            float di = dinv[node];
#pragma unroll
            for (int nt = 0; nt < 4; nt++)
                Y[(size_t)node * DIMH + nt * 16 + m] = __float2half(di * acc[nt][r]);
        }
    }
}

// ---- agg1 + fused conv2 GEMM (R12 proven) ----
__global__ __launch_bounds__(256) void k_agg1f(const __half* __restrict__ Hin,
                                               const unsigned* __restrict__ rp,
                                               const int2* __restrict__ csr,
                                               const float* __restrict__ dinv,
                                               const float* __restrict__ bias,
                                               const float* __restrict__ W2,
                                               __half* __restrict__ T2, int n) {
    __shared__ float W2s[DIMH * DIMH];   // 16 KB
    __shared__ unsigned hbuf[4][32];     // per-wave h row (64 halves)
    int tid = threadIdx.x;
    for (int i = tid * 4; i < DIMH * DIMH; i += 256 * 4)
        *(float4*)&W2s[i] = *(const float4*)&W2[i];
    __syncthreads();

    int lane = tid & 63;
    int wv = tid >> 6;
    int fp = lane & 31;
    bool hi = lane >= 32;
    const unsigned* HinU = (const unsigned*)Hin;  // 32 uints per row
    int ngroups = (n + 3) >> 2;

    for (int grp = blockIdx.x; grp < ngroups; grp += gridDim.x) {
        int node = grp * 4 + wv;
        if (node >= n) continue;
        unsigned pk = rp[node];
        int p = (int)(pk & 0x3FFFFFFu);
        int iters = (int)(pk >> 26);
        float ax = 0.f, ay = 0.f;
        if (!hi) {
            unsigned su = HinU[(size_t)node * 32 + fp];
            float2 sf = __half22float2(*(__half2*)&su);
            ax = sf.x; ay = sf.y;
        }
        for (int it = 0; it < iters; it++, p += 8) {
            int4 m0 = *(const int4*)&csr[p];
            int4 m1 = *(const int4*)&csr[p + 2];
            int4 m2 = *(const int4*)&csr[p + 4];
            int4 m3 = *(const int4*)&csr[p + 6];
            int   s0 = hi ? m0.z : m0.x;
            float w0 = __int_as_float(hi ? m0.w : m0.y);
            int   s1 = hi ? m1.z : m1.x;
            float w1 = __int_as_float(hi ? m1.w : m1.y);
            int   s2 = hi ? m2.z : m2.x;
            float w2 = __int_as_float(hi ? m2.w : m2.y);
            int   s3 = hi ? m3.z : m3.x;
            float w3 = __int_as_float(hi ? m3.w : m3.y);
            unsigned u0 = HinU[(size_t)s0 * 32 + fp];
            unsigned u1 = HinU[(size_t)s1 * 32 + fp];
            unsigned u2 = HinU[(size_t)s2 * 32 + fp];
            unsigned u3 = HinU[(size_t)s3 * 32 + fp];
            float2 f0 = __half22float2(*(__half2*)&u0);
            float2 f1 = __half22float2(*(__half2*)&u1);
            float2 f2 = __half22float2(*(__half2*)&u2);
            float2 f3 = __half22float2(*(__half2*)&u3);
            ax += w0 * f0.x; ay += w0 * f0.y;
            ax += w1 * f1.x; ay += w1 * f1.y;
            ax += w2 * f2.x; ay += w2 * f2.y;
            ax += w3 * f3.x; ay += w3 * f3.y;
        }
        ax += __shfl_xor(ax, 32, 64);
        ay += __shfl_xor(ay, 32, 64);
        float di = dinv[node];
        if (!hi) {
            float vx = di * ax + bias[2 * fp];
            float vy = di * ay + bias[2 * fp + 1];
            vx = vx > 0.f ? vx : 0.f;
            vy = vy > 0.f ? vy : 0.f;
            __half2 hh = __floats2half2_rn(vx, vy);
            hbuf[wv][fp] = *(unsigned*)&hh;
        }
        float acc2 = 0.f;
        const unsigned* hb = hbuf[wv];
#pragma unroll
        for (int k8 = 0; k8 < 8; k8++) {
            uint4 hc = *(const uint4*)&hb[k8 * 4];
            float2 g0 = __half22float2(*(__half2*)&hc.x);
            float2 g1 = __half22float2(*(__half2*)&hc.y);
            float2 g2 = __half22float2(*(__half2*)&hc.z);
            float2 g3 = __half22float2(*(__half2*)&hc.w);
            const float* wc = &W2s[(k8 * 8) * DIMH + lane];
            acc2 += g0.x * wc[0 * DIMH] + g0.y * wc[1 * DIMH]
                  + g1.x * wc[2 * DIMH] + g1.y * wc[3 * DIMH]
                  + g2.x * wc[4 * DIMH] + g2.y * wc[5 * DIMH]
                  + g3.x * wc[6 * DIMH] + g3.y * wc[7 * DIMH];
        }
        T2[(size_t)node * DIMH + lane] = __float2half(di * acc2);
    }
}

// ---- agg2: wave-per-node, paired-lane 32-bit gathers (R8/R11 proven) ----
__global__ __launch_bounds__(256) void k_aggN(const __half* __restrict__ Hin,
                                              const unsigned* __restrict__ rp,
                                              const int2* __restrict__ csr,
                                              const float* __restrict__ dinv,
                                              const float* __restrict__ bias,
                                              __half* __restrict__ Hout, int n) {
    int lane = threadIdx.x & 63;
    int wv = threadIdx.x >> 6;
    int node = blockIdx.x * 4 + wv;
    if (node >= n) return;
    unsigned pk = rp[node];
    int p = (int)(pk & 0x3FFFFFFu);
    int iters = (int)(pk >> 26);
    int fp = lane & 31;
    bool hi = lane >= 32;
    const unsigned* HinU = (const unsigned*)Hin;
    float ax = 0.f, ay = 0.f;
    if (!hi) {
        unsigned su = HinU[(size_t)node * 32 + fp];
        float2 sf = __half22float2(*(__half2*)&su);
        ax = sf.x; ay = sf.y;
    }
    for (int it = 0; it < iters; it++, p += 8) {
        int4 m0 = *(const int4*)&csr[p];
        int4 m1 = *(const int4*)&csr[p + 2];
        int4 m2 = *(const int4*)&csr[p + 4];
        int4 m3 = *(const int4*)&csr[p + 6];
        int   s0 = hi ? m0.z : m0.x;
        float w0 = __int_as_float(hi ? m0.w : m0.y);
        int   s1 = hi ? m1.z : m1.x;
        float w1 = __int_as_float(hi ? m1.w : m1.y);
        int   s2 = hi ? m2.z : m2.x;
        float w2 = __int_as_float(hi ? m2.w : m2.y);
        int   s3 = hi ? m3.z : m3.x;
        float w3 = __int_as_float(hi ? m3.w : m3.y);
        unsigned u0 = HinU[(size_t)s0 * 32 + fp];
        unsigned u1 = HinU[(size_t)s1 * 32 + fp];
        unsigned u2 = HinU[(size_t)s2 * 32 + fp];
        unsigned u3 = HinU[(size_t)s3 * 32 + fp];
        float2 f0 = __half22float2(*(__half2*)&u0);
        float2 f1 = __half22float2(*(__half2*)&u1);
        float2 f2 = __half22float2(*(__half2*)&u2);
        float2 f3 = __half22float2(*(__half2*)&u3);
        ax += w0 * f0.x; ay += w0 * f0.y;
        ax += w1 * f1.x; ay += w1 * f1.y;
        ax += w2 * f2.x; ay += w2 * f2.y;
        ax += w3 * f3.x; ay += w3 * f3.y;
    }
    ax += __shfl_xor(ax, 32, 64);
    ay += __shfl_xor(ay, 32, 64);
    if (!hi) {
        float di = dinv[node];
        float vx = di * ax + bias[2 * fp];
        float vy = di * ay + bias[2 * fp + 1];
        vx = vx > 0.f ? vx : 0.f;
        vy = vy > 0.f ? vy : 0.f;
        __half2 o = __floats2half2_rn(vx, vy);
        *(__half2*)&Hout[(size_t)node * DIMH + 2 * fp] = o;
    }
}

// ---- mean-pool (b sorted, fp16 in): per-wave chunk, flush on change ----
__global__ __launch_bounds__(256) void k_pool(const __half* __restrict__ Hin,
                                              const int* __restrict__ b,
                                              float* __restrict__ sums,
                                              float* __restrict__ cntG, int n) {
    const int CHUNK = 64;
    int lane = threadIdx.x & 63;
    int wave = threadIdx.x >> 6;
    int start = (blockIdx.x * 4 + wave) * CHUNK;
    if (start >= n) return;
    int end = min(start + CHUNK, n);
    float acc = 0.f;
    int g_cur = b[start];
    int cnt_local = 0;
    for (int i = start; i < end; i++) {
        int g = b[i];
        if (g != g_cur) {
            atomicAdd(&sums[g_cur * DIMH + lane], acc);
            if (lane == 0) atomicAdd(&cntG[g_cur], (float)cnt_local);
            acc = 0.f;
            cnt_local = 0;
            g_cur = g;
        }
        acc += __half2float(Hin[(size_t)i * DIMH + lane]);
        cnt_local++;
    }
    atomicAdd(&sums[g_cur * DIMH + lane], acc);
    if (lane == 0) atomicAdd(&cntG[g_cur], (float)cnt_local);
}

// ---- head MLP ----
__global__ __launch_bounds__(64) void k_mlp(const float* __restrict__ sums,
                                            const float* __restrict__ cntG,
                                            const float* __restrict__ Wm1,
                                            const float* __restrict__ bm1,
                                            const float* __restrict__ Wm2,
                                            const float* __restrict__ bm2,
                                            float* __restrict__ out, int G) {
    int g = threadIdx.x;
    if (g >= G) return;
    float c = cntG[g];
    float inv = 1.f / (c > 1.f ? c : 1.f);
    float pooled[DIMH];
#pragma unroll
    for (int k = 0; k < DIMH; k++) pooled[k] = sums[g * DIMH + k] * inv;
    float o = 0.f;
    for (int j = 0; j < 32; j++) {
        float t = bm1[j];
#pragma unroll
        for (int k = 0; k < DIMH; k++) t += pooled[k] * Wm1[k * 32 + j];
        t = t > 0.f ? t : 0.f;
        o += t * Wm2[j];
    }
    out[g] = o + bm2[0];
}

// ============================== launch ==============================

extern "C" void kernel_launch(void* const* d_in, const int* in_sizes, int n_in,
                              void* d_out, int out_size, void* d_ws, size_t ws_size,
                              hipStream_t stream) {
    const float* x   = (const float*)d_in[0];
    const int*   ei  = (const int*)d_in[1];
    const float* ew  = (const float*)d_in[2];
    const int*   bvec= (const int*)d_in[3];
    const float* W1  = (const float*)d_in[4];
    const float* b1  = (const float*)d_in[5];
    const float* W2  = (const float*)d_in[6];
    const float* b2  = (const float*)d_in[7];
    const float* Wm1 = (const float*)d_in[8];
    const float* bm1 = (const float*)d_in[9];
    const float* Wm2 = (const float*)d_in[10];
    const float* bm2 = (const float*)d_in[11];
    float* out = (float*)d_out;

    const int E = in_sizes[2];
    const int N = in_sizes[3];
    const int G = out_size;
    const int* row = ei;
    const int* col = ei + E;
    const int nbuck = (N + BSZ - 1) >> BSH;   // 782 for N=100000

    char* p = (char*)d_ws;
    auto alloc = [&](size_t bytes) {
        void* r = (void*)p;
        p += (bytes + 255) & ~(size_t)255;
        return r;
    };

    unsigned long long* part = (unsigned long long*)alloc((size_t)nbuck * ESTRIDE * 8);
    int2*  csr    = (int2*)alloc((size_t)nbuck * CSTRIDE * 8);
    unsigned* rp  = (unsigned*)alloc((size_t)N * 4);
    float* dinv   = (float*)alloc((size_t)N * 4);
    __half* hA    = (__half*)alloc((size_t)N * DIMH * 2);  // T1, then conv2 out
    __half* hB    = (__half*)alloc((size_t)N * DIMH * 2);  // T2
    // zero region: [cursor | sums | cntG] -> one memset
    int zeroInts  = nbuck + G * DIMH + G;
    int* cursor   = (int*)alloc((size_t)zeroInts * 4);
    float* sums   = (float*)(cursor + nbuck);
    float* cntG   = sums + G * DIMH;

    hipMemsetAsync(cursor, 0, (size_t)zeroInts * 4, stream);

    const int PB = (E + EPB - 1) / EPB;       // 391 partition blocks
    const int NT = (N + 15) / 16;             // 6250 node tiles

    // 1. partition + sort -> padded CSR, packed row_ptr, dinv
    k_part<<<PB, 512, 0, stream>>>(row, col, ew, cursor, part, E, nbuck);
    k_sortB<<<nbuck, 256, 0, stream>>>(part, cursor, csr, rp, dinv, N);

    // 2. conv1 GEMM (MFMA) -> T1 (hA)
    k_gemm_mfma<<<(NT + 3) / 4, 256, 0, stream>>>(x, W1, dinv, hA, N);

    // 3. agg1 + fused conv2 GEMM -> T2 (hB)
    k_agg1f<<<4096, 256, 0, stream>>>(hA, rp, csr, dinv, b1, W2, hB, N);

    // 4. agg2 -> conv2 output (hA, T1 dead)
    k_aggN<<<(N + 3) / 4, 256, 0, stream>>>(hB, rp, csr, dinv, b2, hA, N);

    // 5. pool + head
    k_pool<<<(N + 255) / 256, 256, 0, stream>>>(hA, bvec, sums, cntG, N);
    k_mlp<<<1, 64, 0, stream>>>(sums, cntG, Wm1, bm1, Wm2, bm2, out, G);
}